// Round 1
// baseline (677.948 us; speedup 1.0000x reference)
//
#include <hip/hip_runtime.h>

#define BB 512
#define TT 200
#define VV 2048
#define EE 20
#define HH 100
#define G4 400   // 4*H
#define II 64
#define AA 32

// ---------------- Kernel 1: embedding GEMM ----------------
// emb[b,t,:] = batch[b,t,:] @ W_emb^T + b_emb, skipping rows with t >= len[b].
#define K1_ROWS 128
#define K1_KT   64
#define K1_STRIDE 68   // padded floats per row in LDS (68 mod 32 = 4-spread, 16B aligned)

__global__ __launch_bounds__(128) void k1_embed(
    const float* __restrict__ batch, const int* __restrict__ lengths,
    const float* __restrict__ W_emb, const float* __restrict__ b_emb,
    float* __restrict__ emb)
{
    __shared__ float tile[K1_ROWS * K1_STRIDE];
    __shared__ float wch[K1_KT * EE];      // [k][e]
    __shared__ int   valid[K1_ROWS];

    const int tid  = threadIdx.x;
    const int row0 = blockIdx.x * K1_ROWS;

    {
        int grow = row0 + tid;             // tid < 128 == K1_ROWS
        int b = grow / TT;
        int t = grow - b * TT;
        valid[tid] = (t < lengths[b]) ? 1 : 0;
    }
    __syncthreads();

    float acc[EE];
#pragma unroll
    for (int e = 0; e < EE; ++e) acc[e] = 0.f;

    const int my_valid = valid[tid];

    for (int k0 = 0; k0 < VV; k0 += K1_KT) {
        __syncthreads();   // protect LDS reuse
        // stage batch tile: 128 rows x 64 floats = 2048 float4, 16 per thread
#pragma unroll
        for (int i = 0; i < 16; ++i) {
            int idx = tid + i * 128;       // float4 index
            int r = idx >> 4;              // 16 float4 per row
            int q = idx & 15;
            float4 v = make_float4(0.f, 0.f, 0.f, 0.f);
            if (valid[r]) {
                const float* src = batch + (size_t)(row0 + r) * VV + k0 + q * 4;
                v = *reinterpret_cast<const float4*>(src);
            }
            *reinterpret_cast<float4*>(&tile[r * K1_STRIDE + q * 4]) = v;
        }
        // stage W chunk transposed [k][e]: 1280 floats, 10 per thread
#pragma unroll
        for (int i = 0; i < 10; ++i) {
            int idx = tid + i * 128;
            int e = idx / K1_KT;
            int k = idx - e * K1_KT;
            wch[k * EE + e] = W_emb[(size_t)e * VV + k0 + k];
        }
        __syncthreads();
        if (my_valid) {
            for (int kq = 0; kq < K1_KT / 4; ++kq) {
                float4 tb = *reinterpret_cast<const float4*>(&tile[tid * K1_STRIDE + kq * 4]);
                const float* wbase = &wch[kq * 4 * EE];
#pragma unroll
                for (int kk = 0; kk < 4; ++kk) {
                    float tvv = (kk == 0) ? tb.x : (kk == 1) ? tb.y : (kk == 2) ? tb.z : tb.w;
                    const float* wk = wbase + kk * EE;
#pragma unroll
                    for (int e = 0; e < EE; e += 4) {
                        float4 wv = *reinterpret_cast<const float4*>(wk + e);
                        acc[e + 0] += tvv * wv.x;
                        acc[e + 1] += tvv * wv.y;
                        acc[e + 2] += tvv * wv.z;
                        acc[e + 3] += tvv * wv.w;
                    }
                }
            }
        }
    }

    if (my_valid) {
        int grow = row0 + tid;
        float outv[EE];
#pragma unroll
        for (int e = 0; e < EE; ++e) outv[e] = acc[e] + b_emb[e];
        float* dst = emb + (size_t)grow * EE;
#pragma unroll
        for (int e = 0; e < EE; e += 4) {
            *reinterpret_cast<float4*>(dst + e) =
                make_float4(outv[e], outv[e + 1], outv[e + 2], outv[e + 3]);
        }
    }
}

// ---------------- Kernel 2: LSTM scan + gather + MLP (fused) ----------------
// 256 blocks x 512 threads; block handles batches (2b, 2b+1).
// Thread tid<400 owns gate row tid; its W_ih row (20) + W_hh row (100) live in VGPRs.
// h broadcast via LDS; c in registers of update threads (tid<200).

__device__ __forceinline__ float fast_sig(float x) {
    return 1.f / (1.f + __expf(-x));
}
__device__ __forceinline__ float fast_tanh(float x) {
    x = fminf(fmaxf(x, -15.f), 15.f);
    float e = __expf(2.f * x);
    return (e - 1.f) / (e + 1.f);
}

__global__ __launch_bounds__(512) void k2_lstm(
    const float* __restrict__ emb, const int* __restrict__ lengths,
    const float* __restrict__ W_ih, const float* __restrict__ W_hh,
    const float* __restrict__ b_ih, const float* __restrict__ b_hh,
    const float* __restrict__ W1, const float* __restrict__ b1,
    const float* __restrict__ W2, const float* __restrict__ b2,
    const float* __restrict__ h0, const float* __restrict__ c0,
    float* __restrict__ out)
{
    __shared__ float emb_lds[2][TT][EE];   // 32000 B
    __shared__ float h_lds[2][104];
    __shared__ float gates[2][G4];
    __shared__ float hfin[2][104];
    __shared__ float inter[2][II];

    const int tid = threadIdx.x;
    const int b0  = blockIdx.x * 2;
    const int len0 = lengths[b0];
    const int len1 = lengths[b0 + 1];
    const int tmax = (len0 > len1) ? len0 : len1;

    // preload emb for both batches (2000 float4)
    {
        const float4* src = reinterpret_cast<const float4*>(emb + (size_t)b0 * TT * EE);
        float4* dst = reinterpret_cast<float4*>(&emb_lds[0][0][0]);
        for (int i = tid; i < 2 * TT * EE / 4; i += 512) dst[i] = src[i];
    }
    if (tid < 2 * HH) {
        int b = tid / HH, j = tid - b * HH;
        h_lds[b][j] = h0[(size_t)(b0 + b) * HH + j];
    }

    const int r = tid;
    float w[EE + HH];
    float bias = 0.f;
    if (r < G4) {
#pragma unroll
        for (int e = 0; e < EE; ++e) w[e] = W_ih[r * EE + e];
#pragma unroll
        for (int k = 0; k < HH; ++k) w[EE + k] = W_hh[r * HH + k];
        bias = b_ih[r] + b_hh[r];
    }
    float c_reg = 0.f;
    if (tid < 2 * HH) {
        int b = tid / HH, j = tid - b * HH;
        c_reg = c0[(size_t)(b0 + b) * HH + j];
    }
    __syncthreads();

    for (int t = 0; t < tmax; ++t) {
        if (r < G4) {
            float a0 = bias, a1 = bias;
            const float4* e0 = reinterpret_cast<const float4*>(&emb_lds[0][t][0]);
            const float4* e1 = reinterpret_cast<const float4*>(&emb_lds[1][t][0]);
#pragma unroll
            for (int q = 0; q < EE / 4; ++q) {
                float4 x0 = e0[q], x1 = e1[q];
                a0 += w[4 * q + 0] * x0.x + w[4 * q + 1] * x0.y + w[4 * q + 2] * x0.z + w[4 * q + 3] * x0.w;
                a1 += w[4 * q + 0] * x1.x + w[4 * q + 1] * x1.y + w[4 * q + 2] * x1.z + w[4 * q + 3] * x1.w;
            }
            const float4* h0p = reinterpret_cast<const float4*>(&h_lds[0][0]);
            const float4* h1p = reinterpret_cast<const float4*>(&h_lds[1][0]);
#pragma unroll
            for (int q = 0; q < HH / 4; ++q) {
                float4 x0 = h0p[q], x1 = h1p[q];
                a0 += w[EE + 4 * q + 0] * x0.x + w[EE + 4 * q + 1] * x0.y + w[EE + 4 * q + 2] * x0.z + w[EE + 4 * q + 3] * x0.w;
                a1 += w[EE + 4 * q + 0] * x1.x + w[EE + 4 * q + 1] * x1.y + w[EE + 4 * q + 2] * x1.z + w[EE + 4 * q + 3] * x1.w;
            }
            gates[0][r] = a0;
            gates[1][r] = a1;
        }
        __syncthreads();
        if (tid < 2 * HH) {
            int b = tid / HH, j = tid - b * HH;
            float gi = gates[b][j];
            float gf = gates[b][HH + j];
            float gg = gates[b][2 * HH + j];
            float go = gates[b][3 * HH + j];
            c_reg = fast_sig(gf) * c_reg + fast_sig(gi) * fast_tanh(gg);
            float hv = fast_sig(go) * fast_tanh(c_reg);
            h_lds[b][j] = hv;
            int len = b ? len1 : len0;
            if (t == len - 1) hfin[b][j] = hv;
        }
        __syncthreads();
    }

    // fused MLP: inter = relu(hfin @ W1^T + b1); out = inter @ W2^T + b2
    if (tid < 2 * II) {
        int b = tid >> 6, i = tid & 63;
        float a = b1[i];
        const float* w1r = W1 + i * HH;
#pragma unroll
        for (int k = 0; k < HH; k += 4) {
            a += w1r[k] * hfin[b][k] + w1r[k + 1] * hfin[b][k + 1]
               + w1r[k + 2] * hfin[b][k + 2] + w1r[k + 3] * hfin[b][k + 3];
        }
        inter[b][i] = fmaxf(a, 0.f);
    }
    __syncthreads();
    if (tid < 2 * AA) {
        int b = tid >> 5, ai = tid & 31;
        float a = b2[ai];
        const float* w2r = W2 + ai * II;
#pragma unroll
        for (int k = 0; k < II; ++k) a += w2r[k] * inter[b][k];
        out[(size_t)(b0 + b) * AA + ai] = a;
    }
}

extern "C" void kernel_launch(void* const* d_in, const int* in_sizes, int n_in,
                              void* d_out, int out_size, void* d_ws, size_t ws_size,
                              hipStream_t stream) {
    const float* batch  = (const float*)d_in[0];
    const int*   lengths= (const int*)  d_in[1];
    const float* W_emb  = (const float*)d_in[2];
    const float* b_emb  = (const float*)d_in[3];
    const float* W_ih   = (const float*)d_in[4];
    const float* W_hh   = (const float*)d_in[5];
    const float* b_ih   = (const float*)d_in[6];
    const float* b_hh   = (const float*)d_in[7];
    const float* W1     = (const float*)d_in[8];
    const float* b1     = (const float*)d_in[9];
    const float* W2     = (const float*)d_in[10];
    const float* b2     = (const float*)d_in[11];
    const float* h0     = (const float*)d_in[12];
    const float* c0     = (const float*)d_in[13];
    float* out = (float*)d_out;

    float* emb = (float*)d_ws;   // B*T*E*4 = 8.19 MB

    k1_embed<<<(BB * TT) / K1_ROWS, 128, 0, stream>>>(batch, lengths, W_emb, b_emb, emb);
    k2_lstm<<<BB / 2, 512, 0, stream>>>(emb, lengths, W_ih, W_hh, b_ih, b_hh,
                                        W1, b1, W2, b2, h0, c0, out);
}

// Round 2
// 511.030 us; speedup vs baseline: 1.3266x; 1.3266x over previous
//
#include <hip/hip_runtime.h>

#define BB 512
#define TT 200
#define VV 2048
#define EE 20
#define HH 100
#define G4 400   // 4*H
#define II 64
#define AA 32

// ---------------- workspace layout (floats/ints, 4B units) ----------------
// [0 .. 1023]                : off[513] (int prefix sums) + pad
// [1024 .. 1024+40959]       : Wt[2048][20]  (W_emb transposed)
// [1024+40960 .. ]           : emb[512][200][20]
#define WS_WT_OFF  1024
#define WS_EMB_OFF (1024 + VV * EE)

// ---------------- Kernel 0: prefix-sum of lengths + W transpose ----------------
__global__ __launch_bounds__(512) void k0_prep(
    const int* __restrict__ lengths, const float* __restrict__ W_emb,
    int* __restrict__ off, float* __restrict__ Wt)
{
    if (blockIdx.x == 0) {
        __shared__ int s[BB];
        int tid = threadIdx.x;
        s[tid] = lengths[tid];
        __syncthreads();
        for (int d = 1; d < BB; d <<= 1) {
            int v = (tid >= d) ? s[tid - d] : 0;
            __syncthreads();
            if (tid >= d) s[tid] += v;
            __syncthreads();
        }
        off[tid + 1] = s[tid];
        if (tid == 0) off[0] = 0;
    } else {
        int idx = (blockIdx.x - 1) * 512 + threadIdx.x;
        if (idx < VV * EE) {
            int k = idx / EE, e = idx - k * EE;
            Wt[idx] = W_emb[(size_t)e * VV + k];
        }
    }
}

// ---------------- Kernel 1: embedding GEMV, compacted rows, LDS-free ----------------
// One thread per valid (b,t) row. Row data streamed via double-buffered float4
// registers; weights read through the scalar pipe (uniform Wt indices -> s_load).
__global__ __launch_bounds__(256) void k1_embed(
    const float* __restrict__ batch, const int* __restrict__ off,
    const float* __restrict__ Wt, const float* __restrict__ b_emb,
    float* __restrict__ emb)
{
    const int row = blockIdx.x * 256 + threadIdx.x;
    const int Nv  = off[BB];
    const bool active = row < Nv;
    if (!__any(active)) return;

    // binary search: off[b] <= row < off[b+1]
    int b = 0;
    {
        const int r = active ? row : 0;
        int lo = 0, hi = BB;
        while (lo + 1 < hi) {
            int mid = (lo + hi) >> 1;
            if (off[mid] <= r) lo = mid; else hi = mid;
        }
        b = lo;
    }
    const int t = (active ? row : 0) - off[b];
    const float* __restrict__ src = batch + ((size_t)b * TT + t) * VV;

    float acc[EE];
#pragma unroll
    for (int e = 0; e < EE; ++e) acc[e] = 0.f;

    float4 xa[16], xb[16];
#pragma unroll
    for (int i = 0; i < 16; ++i) {
        xa[i] = make_float4(0.f, 0.f, 0.f, 0.f);
        xb[i] = make_float4(0.f, 0.f, 0.f, 0.f);
    }
    if (active) {
        const float4* p = reinterpret_cast<const float4*>(src);
#pragma unroll
        for (int i = 0; i < 16; ++i) xa[i] = p[i];
    }

#pragma unroll 1
    for (int k0 = 0; k0 < VV; k0 += 64) {
        if (active && (k0 + 64 < VV)) {
            const float4* p = reinterpret_cast<const float4*>(src + k0 + 64);
#pragma unroll
            for (int i = 0; i < 16; ++i) xb[i] = p[i];
        }
        const float* __restrict__ w = Wt + (size_t)k0 * EE;  // uniform -> scalar loads
#pragma unroll
        for (int i = 0; i < 16; ++i) {
            const float x0 = xa[i].x, x1 = xa[i].y, x2 = xa[i].z, x3 = xa[i].w;
            const float* wk = w + i * 4 * EE;
#pragma unroll
            for (int e = 0; e < EE; ++e) acc[e] = fmaf(wk[e], x0, acc[e]);
#pragma unroll
            for (int e = 0; e < EE; ++e) acc[e] = fmaf(wk[EE + e], x1, acc[e]);
#pragma unroll
            for (int e = 0; e < EE; ++e) acc[e] = fmaf(wk[2 * EE + e], x2, acc[e]);
#pragma unroll
            for (int e = 0; e < EE; ++e) acc[e] = fmaf(wk[3 * EE + e], x3, acc[e]);
        }
#pragma unroll
        for (int i = 0; i < 16; ++i) xa[i] = xb[i];
    }

    if (active) {
#pragma unroll
        for (int e = 0; e < EE; ++e) acc[e] += b_emb[e];
        float* dst = emb + ((size_t)b * TT + t) * EE;
#pragma unroll
        for (int e = 0; e < EE; e += 4)
            *reinterpret_cast<float4*>(dst + e) =
                make_float4(acc[e], acc[e + 1], acc[e + 2], acc[e + 3]);
    }
}

// ---------------- Kernel 2: LSTM scan + gather + MLP ----------------
// 256 blocks x 512 threads; block handles batches (2b, 2b+1).
// Gate thread tid<400: owns 2 gate rows (2g,2g+1) x one 60-float half of the
// concat [x(20);h(100)]. Partials combined via DPP xor-1 (no LDS).
__device__ __forceinline__ float fast_sig(float x) {
    return 1.f / (1.f + __expf(-x));
}
__device__ __forceinline__ float fast_tanh(float x) {
    x = fminf(fmaxf(x, -15.f), 15.f);
    float e = __expf(2.f * x);
    return (e - 1.f) / (e + 1.f);
}
__device__ __forceinline__ float dpp_xor1_add(float v) {
    int i = __builtin_bit_cast(int, v);
    int p = __builtin_amdgcn_update_dpp(0, i, 0xB1, 0xF, 0xF, true); // quad_perm(1,0,3,2)
    return v + __builtin_bit_cast(float, p);
}

__global__ __launch_bounds__(512) void k2_lstm(
    const float* __restrict__ emb, const int* __restrict__ lengths,
    const float* __restrict__ W_ih, const float* __restrict__ W_hh,
    const float* __restrict__ b_ih, const float* __restrict__ b_hh,
    const float* __restrict__ W1, const float* __restrict__ b1,
    const float* __restrict__ W2, const float* __restrict__ b2,
    const float* __restrict__ h0, const float* __restrict__ c0,
    float* __restrict__ out)
{
    __shared__ float emb_lds[2][TT][EE];   // 32000 B
    __shared__ float xh[2][128];           // [b][c]: c<20 = x_t, 20..119 = h
    __shared__ float gates[2][G4];
    __shared__ float hfin[2][HH];
    __shared__ float inter[2][II];

    const int tid = threadIdx.x;
    const int b0  = blockIdx.x * 2;
    const int len0 = lengths[b0];
    const int len1 = lengths[b0 + 1];
    const int tmax = (len0 > len1) ? len0 : len1;

    // preload emb for both batches (2000 float4)
    {
        const float4* srcp = reinterpret_cast<const float4*>(emb + (size_t)b0 * TT * EE);
        float4* dst = reinterpret_cast<float4*>(&emb_lds[0][0][0]);
        for (int i = tid; i < 2 * TT * EE / 4; i += 512) dst[i] = srcp[i];
    }

    // gate-thread weight setup: rows 2g,2g+1; k-half `half` of [x;h]
    const int g = tid >> 1, half = tid & 1;
    float w0[60], w1[60];
    float bias_own = 0.f;
    if (tid < G4) {
        const int r0 = 2 * g, r1 = 2 * g + 1;
        if (half == 0) {
#pragma unroll
            for (int i = 0; i < EE; ++i) {
                w0[i] = W_ih[r0 * EE + i];
                w1[i] = W_ih[r1 * EE + i];
            }
#pragma unroll
            for (int i = EE; i < 60; ++i) {
                w0[i] = W_hh[r0 * HH + (i - EE)];
                w1[i] = W_hh[r1 * HH + (i - EE)];
            }
        } else {
#pragma unroll
            for (int i = 0; i < 60; ++i) {
                w0[i] = W_hh[r0 * HH + 40 + i];
                w1[i] = W_hh[r1 * HH + 40 + i];
            }
        }
        const int myrow = 2 * g + half;
        bias_own = b_ih[myrow] + b_hh[myrow];
    }

    const int ub = (tid < 2 * HH) ? tid / HH : 0;
    const int uj = (tid < 2 * HH) ? tid - ub * HH : 0;
    float c_reg = 0.f;
    if (tid < 2 * HH) c_reg = c0[(size_t)(b0 + ub) * HH + uj];

    __syncthreads();   // emb_lds ready

    if (tid < 240) {
        int b = tid / 120, c = tid - b * 120;
        int ce = (c < EE) ? c : (EE - 1);
        int ch = (c >= EE) ? (c - EE) : 0;
        float ve = emb_lds[b][0][ce];
        float vh = h0[(size_t)(b0 + b) * HH + ch];
        xh[b][c] = (c < EE) ? ve : vh;
    }
    __syncthreads();

    for (int t = 0; t < tmax; ++t) {
        if (tid < G4) {
            float a00 = 0.f, a01 = 0.f, a10 = 0.f, a11 = 0.f; // [row][batch]
            const float4* p0 = reinterpret_cast<const float4*>(&xh[0][60 * half]);
            const float4* p1 = reinterpret_cast<const float4*>(&xh[1][60 * half]);
#pragma unroll
            for (int q = 0; q < 15; ++q) {
                float4 x0 = p0[q], x1 = p1[q];
                a00 = fmaf(w0[4 * q + 0], x0.x, a00);
                a00 = fmaf(w0[4 * q + 1], x0.y, a00);
                a00 = fmaf(w0[4 * q + 2], x0.z, a00);
                a00 = fmaf(w0[4 * q + 3], x0.w, a00);
                a10 = fmaf(w1[4 * q + 0], x0.x, a10);
                a10 = fmaf(w1[4 * q + 1], x0.y, a10);
                a10 = fmaf(w1[4 * q + 2], x0.z, a10);
                a10 = fmaf(w1[4 * q + 3], x0.w, a10);
                a01 = fmaf(w0[4 * q + 0], x1.x, a01);
                a01 = fmaf(w0[4 * q + 1], x1.y, a01);
                a01 = fmaf(w0[4 * q + 2], x1.z, a01);
                a01 = fmaf(w0[4 * q + 3], x1.w, a01);
                a11 = fmaf(w1[4 * q + 0], x1.x, a11);
                a11 = fmaf(w1[4 * q + 1], x1.y, a11);
                a11 = fmaf(w1[4 * q + 2], x1.z, a11);
                a11 = fmaf(w1[4 * q + 3], x1.w, a11);
            }
            a00 = dpp_xor1_add(a00);
            a10 = dpp_xor1_add(a10);
            a01 = dpp_xor1_add(a01);
            a11 = dpp_xor1_add(a11);
            const int myrow = 2 * g + half;
            gates[0][myrow] = (half ? a10 : a00) + bias_own;
            gates[1][myrow] = (half ? a11 : a01) + bias_own;
        }
        __syncthreads();
        if (tid < 2 * HH) {
            float gi = gates[ub][uj];
            float gf = gates[ub][HH + uj];
            float gg = gates[ub][2 * HH + uj];
            float go = gates[ub][3 * HH + uj];
            c_reg = fast_sig(gf) * c_reg + fast_sig(gi) * fast_tanh(gg);
            float hv = fast_sig(go) * fast_tanh(c_reg);
            xh[ub][EE + uj] = hv;
            int len = ub ? len1 : len0;
            if (t == len - 1) hfin[ub][uj] = hv;
        } else if (tid >= G4 && tid < G4 + 2 * EE) {
            int b = (tid - G4) / EE, e = (tid - G4) - b * EE;
            if (t + 1 < tmax) xh[b][e] = emb_lds[b][t + 1][e];
        }
        __syncthreads();
    }

    // fused MLP: inter = relu(hfin @ W1^T + b1); out = inter @ W2^T + b2
    if (tid < 2 * II) {
        int b = tid >> 6, i = tid & 63;
        float a = b1[i];
        const float* w1r = W1 + i * HH;
#pragma unroll
        for (int k = 0; k < HH; k += 4) {
            a += w1r[k] * hfin[b][k] + w1r[k + 1] * hfin[b][k + 1]
               + w1r[k + 2] * hfin[b][k + 2] + w1r[k + 3] * hfin[b][k + 3];
        }
        inter[b][i] = fmaxf(a, 0.f);
    }
    __syncthreads();
    if (tid < 2 * AA) {
        int b = tid >> 5, ai = tid & 31;
        float a = b2[ai];
        const float* w2r = W2 + ai * II;
#pragma unroll
        for (int k = 0; k < II; ++k) a += w2r[k] * inter[b][k];
        out[(size_t)(b0 + b) * AA + ai] = a;
    }
}

extern "C" void kernel_launch(void* const* d_in, const int* in_sizes, int n_in,
                              void* d_out, int out_size, void* d_ws, size_t ws_size,
                              hipStream_t stream) {
    const float* batch  = (const float*)d_in[0];
    const int*   lengths= (const int*)  d_in[1];
    const float* W_emb  = (const float*)d_in[2];
    const float* b_emb  = (const float*)d_in[3];
    const float* W_ih   = (const float*)d_in[4];
    const float* W_hh   = (const float*)d_in[5];
    const float* b_ih   = (const float*)d_in[6];
    const float* b_hh   = (const float*)d_in[7];
    const float* W1     = (const float*)d_in[8];
    const float* b1     = (const float*)d_in[9];
    const float* W2     = (const float*)d_in[10];
    const float* b2     = (const float*)d_in[11];
    const float* h0     = (const float*)d_in[12];
    const float* c0     = (const float*)d_in[13];
    float* out = (float*)d_out;

    int*   off = (int*)d_ws;
    float* Wt  = (float*)d_ws + WS_WT_OFF;
    float* emb = (float*)d_ws + WS_EMB_OFF;

    k0_prep<<<1 + (VV * EE + 511) / 512, 512, 0, stream>>>(lengths, W_emb, off, Wt);
    k1_embed<<<(BB * TT) / 256, 256, 0, stream>>>(batch, off, Wt, b_emb, emb);
    k2_lstm<<<BB / 2, 512, 0, stream>>>(emb, lengths, W_ih, W_hh, b_ih, b_hh,
                                        W1, b1, W2, b2, h0, c0, out);
}

// Round 3
// 445.347 us; speedup vs baseline: 1.5223x; 1.1475x over previous
//
#include <hip/hip_runtime.h>

#define BB 512
#define TT 200
#define VV 2048
#define EE 20
#define HH 100
#define G4 400   // 4*H
#define II 64
#define AA 32

typedef float vf2 __attribute__((ext_vector_type(2)));

// ---------------- workspace layout (4B units) ----------------
#define WS_WT_OFF  1024
#define WS_EMB_OFF (1024 + VV * EE)

// ---------------- Kernel 0: prefix-sum of lengths + W transpose ----------------
__global__ __launch_bounds__(512) void k0_prep(
    const int* __restrict__ lengths, const float* __restrict__ W_emb,
    int* __restrict__ off, float* __restrict__ Wt)
{
    if (blockIdx.x == 0) {
        __shared__ int s[BB];
        int tid = threadIdx.x;
        s[tid] = lengths[tid];
        __syncthreads();
        for (int d = 1; d < BB; d <<= 1) {
            int v = (tid >= d) ? s[tid - d] : 0;
            __syncthreads();
            if (tid >= d) s[tid] += v;
            __syncthreads();
        }
        off[tid + 1] = s[tid];
        if (tid == 0) off[0] = 0;
    } else {
        int idx = (blockIdx.x - 1) * 512 + threadIdx.x;
        if (idx < VV * EE) {
            int k = idx / EE, e = idx - k * EE;
            Wt[idx] = W_emb[(size_t)e * VV + k];   // Wt[k][e]
        }
    }
}

// ---------------- Kernel 1: embedding GEMV, LDS tile + broadcast weights ----------------
#define R1   128   // rows per block (= threads)
#define KC   64    // k-chunk
#define TSTR 68    // tile row stride (floats): 16B-aligned, even 8/bank for b128

__global__ __launch_bounds__(128) void k1_embed(
    const float* __restrict__ batch, const int* __restrict__ off,
    const float* __restrict__ Wt, const float* __restrict__ b_emb,
    float* __restrict__ emb)
{
    __shared__ float tile[R1 * TSTR];          // 34816 B
    __shared__ float wch[(KC / 2) * EE * 2];   // [kpair][e][parity], 5120 B
    __shared__ int   roff[R1];

    const int tid  = threadIdx.x;
    const int Nv   = off[BB];
    const int row0 = blockIdx.x * R1;
    if (row0 >= Nv) return;                    // block-uniform exit (before barriers)

    const int row    = row0 + tid;
    const bool active = row < Nv;

    int b = 0;
    {
        const int r = active ? row : 0;
        int lo = 0, hi = BB;
        while (lo + 1 < hi) {
            int mid = (lo + hi) >> 1;
            if (off[mid] <= r) lo = mid; else hi = mid;
        }
        b = lo;
    }
    const int t = (active ? row : 0) - off[b];
    roff[tid] = b * TT + t;
    __syncthreads();

    // 16 coalesced source pointers: rows (tid>>4)+8i, 16B column (tid&15)*4
    const float* srcp[16];
#pragma unroll
    for (int i = 0; i < 16; ++i) {
        int r = (tid >> 4) + 8 * i;
        srcp[i] = batch + (size_t)roff[r] * VV + (tid & 15) * 4;
    }

    vf2 acc[EE];
#pragma unroll
    for (int e = 0; e < EE; ++e) { acc[e].x = 0.f; acc[e].y = 0.f; }

#pragma unroll 1
    for (int c0 = 0; c0 < VV; c0 += KC) {
        __syncthreads();
        // stage batch tile (coalesced 256B segments per row)
#pragma unroll
        for (int i = 0; i < 16; ++i) {
            int r = (tid >> 4) + 8 * i;
            float4 v = *reinterpret_cast<const float4*>(srcp[i] + c0);
            *reinterpret_cast<float4*>(&tile[r * TSTR + (tid & 15) * 4]) = v;
        }
        // stage weight chunk into [kpair][e][parity]
#pragma unroll
        for (int i = 0; i < 10; ++i) {
            int l = tid + i * 128;             // l = k*EE + e
            int k = l / EE, e = l - k * EE;
            wch[(k >> 1) * (2 * EE) + e * 2 + (k & 1)] = Wt[(size_t)c0 * EE + l];
        }
        __syncthreads();
        // compute: thread-per-row, pk-FMA over k-pairs
#pragma unroll
        for (int p = 0; p < 16; ++p) {
            float4 xv = *reinterpret_cast<const float4*>(&tile[tid * TSTR + p * 4]);
            vf2 xlo, xhi;
            xlo.x = xv.x; xlo.y = xv.y;
            xhi.x = xv.z; xhi.y = xv.w;
            const float* wlo = &wch[(2 * p) * (2 * EE)];
            const float* whi = &wch[(2 * p + 1) * (2 * EE)];
#pragma unroll
            for (int e2 = 0; e2 < EE / 2; ++e2) {
                float4 wv = *reinterpret_cast<const float4*>(wlo + e2 * 4);
                vf2 w0, w1;
                w0.x = wv.x; w0.y = wv.y;
                w1.x = wv.z; w1.y = wv.w;
                acc[2 * e2]     = __builtin_elementwise_fma(w0, xlo, acc[2 * e2]);
                acc[2 * e2 + 1] = __builtin_elementwise_fma(w1, xlo, acc[2 * e2 + 1]);
            }
#pragma unroll
            for (int e2 = 0; e2 < EE / 2; ++e2) {
                float4 wv = *reinterpret_cast<const float4*>(whi + e2 * 4);
                vf2 w0, w1;
                w0.x = wv.x; w0.y = wv.y;
                w1.x = wv.z; w1.y = wv.w;
                acc[2 * e2]     = __builtin_elementwise_fma(w0, xhi, acc[2 * e2]);
                acc[2 * e2 + 1] = __builtin_elementwise_fma(w1, xhi, acc[2 * e2 + 1]);
            }
        }
    }

    if (active) {
        float o[EE];
#pragma unroll
        for (int e = 0; e < EE; ++e) o[e] = acc[e].x + acc[e].y + b_emb[e];
        float* dst = emb + (size_t)(b * TT + t) * EE;
#pragma unroll
        for (int e = 0; e < EE; e += 4)
            *reinterpret_cast<float4*>(dst + e) = make_float4(o[e], o[e+1], o[e+2], o[e+3]);
    }
}

// ---------------- Kernel 2: LSTM scan (1 barrier/step) + gather + MLP ----------------
// 256 blocks x 448 threads; block = batches (2b,2b+1).
// Gate thread tid<400: (j = tid>>2, q = tid&3) owns ALL 4 gates of h-index j
// over k-quarter q (32 of 128 padded concat [x(20);h(100);0(8)]).
// Quad DPP butterfly sums quarters; lanes q<2 do the cell update for batch q.
__device__ __forceinline__ float fast_sig(float x) { return 1.f / (1.f + __expf(-x)); }
__device__ __forceinline__ float fast_tanh(float x) {
    x = fminf(fmaxf(x, -15.f), 15.f);
    float e = __expf(2.f * x);
    return (e - 1.f) / (e + 1.f);
}
__device__ __forceinline__ float dpp_xor1_add(float v) {
    int p = __builtin_amdgcn_update_dpp(0, __builtin_bit_cast(int, v), 0xB1, 0xF, 0xF, true);
    return v + __builtin_bit_cast(float, p);
}
__device__ __forceinline__ float dpp_xor2_add(float v) {
    int p = __builtin_amdgcn_update_dpp(0, __builtin_bit_cast(int, v), 0x4E, 0xF, 0xF, true);
    return v + __builtin_bit_cast(float, p);
}
#define QSTR 36   // quarter stride in xh buffer (floats): conflict-free across q

__global__ __launch_bounds__(448) void k2_lstm(
    const float* __restrict__ emb, const int* __restrict__ lengths,
    const float* __restrict__ W_ih, const float* __restrict__ W_hh,
    const float* __restrict__ b_ih, const float* __restrict__ b_hh,
    const float* __restrict__ W1, const float* __restrict__ b1,
    const float* __restrict__ W2, const float* __restrict__ b2,
    const float* __restrict__ h0, const float* __restrict__ c0,
    float* __restrict__ out)
{
    __shared__ float xhbuf[2][2][160];   // [buf][batch][4 quarters x QSTR]
    __shared__ float hfin[2][HH];
    __shared__ float inter[2][II];

    const int tid = threadIdx.x;
    const int b0  = blockIdx.x * 2;
    const int len0 = lengths[b0];
    const int len1 = lengths[b0 + 1];
    const int tmax = (len0 > len1) ? len0 : len1;

    const int j = tid >> 2, q = tid & 3;

    // zero xh buffers (incl. pads that stay zero forever)
    for (int i = tid; i < 2 * 2 * 160; i += 448) (&xhbuf[0][0][0])[i] = 0.f;

    // per-thread weights: 4 gates x 32 concat-cols of quarter q
    vf2 w2[4][16];
    float biasv[4];
    float c_reg = 0.f;
    int lenq = 0;
    if (tid < G4) {
        const int rr[4] = { j, HH + j, 2 * HH + j, 3 * HH + j };
#pragma unroll
        for (int g = 0; g < 4; ++g) {
            const int r = rr[g];
#pragma unroll
            for (int mp = 0; mp < 16; ++mp) {
                int k = q * 32 + mp * 2;     // even; region splits at 20,120 (even)
                float2 v;
                if (k + 1 < EE)          v = *reinterpret_cast<const float2*>(&W_ih[r * EE + k]);
                else if (k + 1 < EE + HH) v = *reinterpret_cast<const float2*>(&W_hh[r * HH + k - EE]);
                else                     v = make_float2(0.f, 0.f);
                w2[g][mp].x = v.x; w2[g][mp].y = v.y;
            }
            biasv[g] = b_ih[r] + b_hh[r];
        }
        if (q < 2) c_reg = c0[(size_t)(b0 + q) * HH + j];
        lenq = (q == 0) ? len0 : len1;
    }
    __syncthreads();   // zeros done before init writes

    float xreg = 0.f;
    if (tid < G4) {
        if (q < 2) {
            int i = EE + j;
            xhbuf[0][q][(i >> 5) * QSTR + (i & 31)] = h0[(size_t)(b0 + q) * HH + j];
        }
    } else if (tid < G4 + 2 * EE) {
        const int wdx = tid - G4, bw = wdx / EE, e = wdx - bw * EE;
        const float* ep = emb + (size_t)(b0 + bw) * TT * EE;
        xhbuf[0][bw][e] = ep[e];             // x_0 (slot(e)=e, quarter 0)
        xreg = ep[EE + e];                   // prefetch x_1
    }
    __syncthreads();

#pragma unroll 1
    for (int t = 0; t < tmax; ++t) {
        const int cur = t & 1, nxt = cur ^ 1;
        if (tid < G4) {
            vf2 a[4][2];
#pragma unroll
            for (int g = 0; g < 4; ++g) { a[g][0].x=0.f; a[g][0].y=0.f; a[g][1].x=0.f; a[g][1].y=0.f; }
            const float* xc = &xhbuf[cur][0][0];
#pragma unroll
            for (int m8 = 0; m8 < 8; ++m8) {
                float4 x0 = *reinterpret_cast<const float4*>(xc + q * QSTR + m8 * 4);
                float4 x1 = *reinterpret_cast<const float4*>(xc + 160 + q * QSTR + m8 * 4);
                vf2 xl0, xh0, xl1, xh1;
                xl0.x = x0.x; xl0.y = x0.y;  xh0.x = x0.z; xh0.y = x0.w;
                xl1.x = x1.x; xl1.y = x1.y;  xh1.x = x1.z; xh1.y = x1.w;
#pragma unroll
                for (int g = 0; g < 4; ++g) {
                    a[g][0] = __builtin_elementwise_fma(w2[g][2*m8],   xl0, a[g][0]);
                    a[g][0] = __builtin_elementwise_fma(w2[g][2*m8+1], xh0, a[g][0]);
                    a[g][1] = __builtin_elementwise_fma(w2[g][2*m8],   xl1, a[g][1]);
                    a[g][1] = __builtin_elementwise_fma(w2[g][2*m8+1], xh1, a[g][1]);
                }
            }
            float s_[4][2];
#pragma unroll
            for (int g = 0; g < 4; ++g) {
#pragma unroll
                for (int bb = 0; bb < 2; ++bb) {
                    float v = a[g][bb].x + a[g][bb].y;
                    v = dpp_xor1_add(v);
                    v = dpp_xor2_add(v);
                    s_[g][bb] = v;
                }
            }
            if (q < 2) {
                float gi = s_[0][q] + biasv[0];
                float gf = s_[1][q] + biasv[1];
                float gg = s_[2][q] + biasv[2];
                float go = s_[3][q] + biasv[3];
                c_reg = fast_sig(gf) * c_reg + fast_sig(gi) * fast_tanh(gg);
                float hv = fast_sig(go) * fast_tanh(c_reg);
                int i = EE + j;
                xhbuf[nxt][q][(i >> 5) * QSTR + (i & 31)] = hv;
                if (t == lenq - 1) hfin[q][j] = hv;
            }
        } else if (tid < G4 + 2 * EE) {
            const int wdx = tid - G4, bw = wdx / EE, e = wdx - bw * EE;
            xhbuf[nxt][bw][e] = xreg;        // x_{t+1}
            xreg = (t + 2 < TT)
                 ? emb[((size_t)(b0 + bw) * TT + (t + 2)) * EE + e] : 0.f;
        }
        __syncthreads();
    }

    // fused MLP
    if (tid < 2 * II) {
        int bb = tid >> 6, i = tid & 63;
        float a = b1[i];
        const float* w1r = W1 + i * HH;
#pragma unroll
        for (int k = 0; k < HH; k += 4) {
            a += w1r[k] * hfin[bb][k] + w1r[k+1] * hfin[bb][k+1]
               + w1r[k+2] * hfin[bb][k+2] + w1r[k+3] * hfin[bb][k+3];
        }
        inter[bb][i] = fmaxf(a, 0.f);
    }
    __syncthreads();
    if (tid < 2 * AA) {
        int bb = tid >> 5, ai = tid & 31;
        float a = b2[ai];
        const float* w2r = W2 + ai * II;
#pragma unroll
        for (int k = 0; k < II; ++k) a += w2r[k] * inter[bb][k];
        out[(size_t)(b0 + bb) * AA + ai] = a;
    }
}

extern "C" void kernel_launch(void* const* d_in, const int* in_sizes, int n_in,
                              void* d_out, int out_size, void* d_ws, size_t ws_size,
                              hipStream_t stream) {
    const float* batch  = (const float*)d_in[0];
    const int*   lengths= (const int*)  d_in[1];
    const float* W_emb  = (const float*)d_in[2];
    const float* b_emb  = (const float*)d_in[3];
    const float* W_ih   = (const float*)d_in[4];
    const float* W_hh   = (const float*)d_in[5];
    const float* b_ih   = (const float*)d_in[6];
    const float* b_hh   = (const float*)d_in[7];
    const float* W1     = (const float*)d_in[8];
    const float* b1     = (const float*)d_in[9];
    const float* W2     = (const float*)d_in[10];
    const float* b2     = (const float*)d_in[11];
    const float* h0     = (const float*)d_in[12];
    const float* c0     = (const float*)d_in[13];
    float* out = (float*)d_out;

    int*   off = (int*)d_ws;
    float* Wt  = (float*)d_ws + WS_WT_OFF;
    float* emb = (float*)d_ws + WS_EMB_OFF;

    k0_prep<<<1 + (VV * EE + 511) / 512, 512, 0, stream>>>(lengths, W_emb, off, Wt);
    k1_embed<<<(BB * TT + R1 - 1) / R1, R1, 0, stream>>>(batch, off, Wt, b_emb, emb);
    k2_lstm<<<BB / 2, 448, 0, stream>>>(emb, lengths, W_ih, W_hh, b_ih, b_hh,
                                        W1, b1, W2, b2, h0, c0, out);
}